// Round 1
// baseline (202.973 us; speedup 1.0000x reference)
//
#include <hip/hip_runtime.h>
#include <hip/hip_bf16.h>

// Problem constants (from reference)
#define N_PARENT 16384
#define N_CHILD (8 * N_PARENT)   // 131072
#define CC 128                   // channels
#define KK 27                    // stencil taps

// GEMM tiling
#define BM 128                   // child rows per block
#define BK 64                    // c-slice per stage (half a channel row)
#define NSTAGE (KK * 2)          // 54 stages

// ws layout (bf16 element offsets)
#define XB_OFF 0
#define XB_ELEMS (N_PARENT * CC)             // 2,097,152
#define WT_OFF XB_ELEMS
#define WT_ELEMS (KK * CC * CC)              // 442,368
#define ZR_OFF (WT_OFF + WT_ELEMS)
#define ZR_ELEMS 128

typedef __attribute__((ext_vector_type(8))) __bf16 bf16x8;
typedef __attribute__((ext_vector_type(4))) float f32x4;

__device__ __forceinline__ void gll16(const void* g, void* l) {
  __builtin_amdgcn_global_load_lds(
      (const __attribute__((address_space(1))) unsigned int*)g,
      (__attribute__((address_space(3))) unsigned int*)l,
      16, 0, 0);
}

// Cast x to bf16, build w^T[k][d][c] in bf16, zero row. Runs every launch
// (ws is poisoned before timing; kernel_launch must be deterministic).
__global__ void prep_kernel(const float* __restrict__ x,
                            const float* __restrict__ w,
                            __hip_bfloat16* __restrict__ ws) {
  const int stride = gridDim.x * blockDim.x;
  const int tid = blockIdx.x * blockDim.x + threadIdx.x;
  for (int i = tid; i < XB_ELEMS; i += stride)
    ws[XB_OFF + i] = __float2bfloat16(x[i]);
  for (int j = tid; j < WT_ELEMS; j += stride) {
    const int k = j / (CC * CC);
    const int rem = j - k * CC * CC;
    const int d = rem >> 7;   // output channel
    const int c = rem & 127;  // input channel
    ws[WT_OFF + j] = __float2bfloat16(w[k * CC * CC + c * CC + d]);
  }
  if (tid < ZR_ELEMS) ws[ZR_OFF + tid] = __float2bfloat16(0.0f);
}

__global__ __launch_bounds__(256, 2) void upconv_kernel(
    const int* __restrict__ neigh,
    const __hip_bfloat16* __restrict__ ws,
    const float* __restrict__ bias,
    float* __restrict__ out) {
  // Double-buffered tiles. A: gathered child features. B: w^T slice [d][c].
  __shared__ __align__(16) __hip_bfloat16 As[2][BM][BK];   // 32 KB
  __shared__ __align__(16) __hip_bfloat16 Bs[2][CC][BK];   // 32 KB
  __shared__ short ridx[BM * KK];                          // 6.75 KB

  const __hip_bfloat16* xb = ws + XB_OFF;
  const __hip_bfloat16* wT = ws + WT_OFF;
  const __hip_bfloat16* zr = ws + ZR_OFF;

  const int tid = threadIdx.x;
  const int wv = tid >> 6;   // wave 0..3
  const int l = tid & 63;    // lane
  const int row0 = blockIdx.x * BM;

  // Preload all neighbor indices for this block's 128 rows (coalesced),
  // pre-shifted to parent rows; -1 = missing neighbor.
  for (int j = tid; j < BM * KK; j += 256) {
    const int nv = neigh[row0 * KK + j];
    ridx[j] = (short)((nv >= 0) ? (nv >> 3) : -1);
  }
  __syncthreads();

  const int lr = l & 15;          // frag row/col within 16
  const int lk = (l >> 4) * 8;    // frag k-chunk offset (elements)
  const int lrow = l >> 3;        // staging: row within 8-row group
  const int lcol = (l & 7) * 8;   // staging: element offset within 64-elt row

  f32x4 acc[2][8] = {};

  // --- staging: 8 global_load_lds(16B) per wave per stage -----------------
  auto stage = [&](int buf, int s) {
    const int k = s >> 1;
    const int hOff = (s & 1) << 6;  // 0 or 64
#pragma unroll
    for (int i = 0; i < 4; ++i) {
      const int rg = wv * 32 + i * 8;        // 8-row group base
      const int rr = rg + lrow;
      const int ix = (int)ridx[rr * KK + k];
      const __hip_bfloat16* ga =
          (ix >= 0) ? (xb + (size_t)ix * CC + hOff + lcol) : (zr + lcol);
      gll16(ga, &As[buf][rg][0]);
      const __hip_bfloat16* gb =
          wT + (size_t)k * (CC * CC) + (size_t)rr * CC + hOff + lcol;
      gll16(gb, &Bs[buf][rg][0]);
    }
  };

  // --- compute: 20 ds_read_b128 + 32 MFMA per wave per stage --------------
  auto compute = [&](int buf) {
#pragma unroll
    for (int kc = 0; kc < 2; ++kc) {
      bf16x8 a[2], bb[8];
#pragma unroll
      for (int m = 0; m < 2; ++m)
        a[m] = *reinterpret_cast<const bf16x8*>(
            &As[buf][wv * 32 + m * 16 + lr][kc * 32 + lk]);
#pragma unroll
      for (int n = 0; n < 8; ++n)
        bb[n] = *reinterpret_cast<const bf16x8*>(
            &Bs[buf][n * 16 + lr][kc * 32 + lk]);
#pragma unroll
      for (int m = 0; m < 2; ++m)
#pragma unroll
        for (int n = 0; n < 8; ++n)
          acc[m][n] =
              __builtin_amdgcn_mfma_f32_16x16x32_bf16(a[m], bb[n], acc[m][n],
                                                      0, 0, 0);
    }
  };

  // --- main loop: dbuf, 1 barrier per stage -------------------------------
  stage(0, 0);
  __syncthreads();  // drains vmcnt(0): buf0 ready
  int cur = 0;
#pragma unroll 2
  for (int s = 0; s < NSTAGE; ++s) {
    if (s + 1 < NSTAGE) stage(cur ^ 1, s + 1);
    compute(cur);
    __syncthreads();  // drains stage loads; protects buf reuse
    cur ^= 1;
  }

  // --- epilogue: C/D layout col=lane&15, row=(lane>>4)*4+q ---------------
  float bv[8];
#pragma unroll
  for (int n = 0; n < 8; ++n) bv[n] = bias[n * 16 + lr];
  const int rbase = row0 + wv * 32 + (l >> 4) * 4;
#pragma unroll
  for (int m = 0; m < 2; ++m)
#pragma unroll
    for (int n = 0; n < 8; ++n)
#pragma unroll
      for (int q = 0; q < 4; ++q)
        out[(size_t)(rbase + m * 16 + q) * CC + n * 16 + lr] =
            acc[m][n][q] + bv[n];
}

extern "C" void kernel_launch(void* const* d_in, const int* in_sizes, int n_in,
                              void* d_out, int out_size, void* d_ws,
                              size_t ws_size, hipStream_t stream) {
  const float* x = (const float*)d_in[0];
  const float* w = (const float*)d_in[1];
  const float* b = (const float*)d_in[2];
  const int* neigh = (const int*)d_in[3];
  __hip_bfloat16* ws = (__hip_bfloat16*)d_ws;
  float* out = (float*)d_out;

  hipLaunchKernelGGL(prep_kernel, dim3(512), dim3(256), 0, stream, x, w, ws);
  hipLaunchKernelGGL(upconv_kernel, dim3(N_CHILD / BM), dim3(256), 0, stream,
                     neigh, ws, b, out);
}

// Round 2
// 150.039 us; speedup vs baseline: 1.3528x; 1.3528x over previous
//
#include <hip/hip_runtime.h>
#include <hip/hip_bf16.h>

// Problem constants (from reference)
#define N_PARENT 16384
#define N_CHILD (8 * N_PARENT)   // 131072
#define CC 128                   // channels
#define KK 27                    // stencil taps

// GEMM tiling
#define BM 128                   // child rows per block
#define BK 64                    // c-slice per stage (half a channel row)
#define NSTAGE (KK * 2)          // 54 stages

// ws layout (bf16 element offsets)
#define XB_OFF 0
#define XB_ELEMS (N_PARENT * CC)             // 2,097,152
#define WT_OFF XB_ELEMS
#define WT_ELEMS (KK * CC * CC)              // 442,368
#define ZR_OFF (WT_OFF + WT_ELEMS)
#define ZR_ELEMS 128

typedef __attribute__((ext_vector_type(8))) __bf16 bf16x8;
typedef __attribute__((ext_vector_type(4))) float f32x4;

__device__ __forceinline__ void gll16(const void* g, void* l) {
  __builtin_amdgcn_global_load_lds(
      (const __attribute__((address_space(1))) unsigned int*)g,
      (__attribute__((address_space(3))) unsigned int*)l,
      16, 0, 0);
}

// Cast x to bf16, build w^T[k][d][c] in bf16, zero row. Runs every launch
// (ws is poisoned before timing; kernel_launch must be deterministic).
__global__ void prep_kernel(const float* __restrict__ x,
                            const float* __restrict__ w,
                            __hip_bfloat16* __restrict__ ws) {
  const int stride = gridDim.x * blockDim.x;
  const int tid = blockIdx.x * blockDim.x + threadIdx.x;
  for (int i = tid; i < XB_ELEMS; i += stride)
    ws[XB_OFF + i] = __float2bfloat16(x[i]);
  for (int j = tid; j < WT_ELEMS; j += stride) {
    const int k = j / (CC * CC);
    const int rem = j - k * CC * CC;
    const int d = rem >> 7;   // output channel
    const int c = rem & 127;  // input channel
    ws[WT_OFF + j] = __float2bfloat16(w[k * CC * CC + c * CC + d]);
  }
  if (tid < ZR_ELEMS) ws[ZR_OFF + tid] = __float2bfloat16(0.0f);
}

// LDS logical layout: tile[row][col] (row stride BK=64 bf16 = 128 B).
// Physical col swizzle: phys_col_elem = log_col_elem ^ ((row&7)*8).
// Staging keeps the LDS dest LINEAR (global_load_lds requirement) and applies
// the inverse permutation on the per-lane GLOBAL source column instead
// (rule #21: both-sides-or-neither).
__global__ __launch_bounds__(256, 2) void upconv_kernel(
    const int* __restrict__ neigh,
    const __hip_bfloat16* __restrict__ ws,
    const float* __restrict__ bias,
    float* __restrict__ out) {
  __shared__ __align__(16) __hip_bfloat16 As[2][BM * BK];   // 32 KB
  __shared__ __align__(16) __hip_bfloat16 Bs[2][CC * BK];   // 32 KB
  __shared__ short ridx[BM * KK];                           // 6.75 KB

  const __hip_bfloat16* xb = ws + XB_OFF;
  const __hip_bfloat16* wT = ws + WT_OFF;
  const __hip_bfloat16* zr = ws + ZR_OFF;

  const int tid = threadIdx.x;
  const int wv = tid >> 6;   // wave 0..3
  const int l = tid & 63;    // lane
  const int wr = wv >> 1;    // wave row (2x2 wave grid, 64x64 per wave)
  const int wc = wv & 1;     // wave col
  const int row0 = blockIdx.x * BM;

  // Preload neighbor indices (coalesced), pre-shifted to parent rows.
  for (int j = tid; j < BM * KK; j += 256) {
    const int nv = neigh[row0 * KK + j];
    ridx[j] = (short)((nv >= 0) ? (nv >> 3) : -1);
  }
  __syncthreads();

  const int lr = l & 15;          // frag row/col within 16
  const int lk = (l >> 4) * 8;    // frag k-chunk offset (elements)
  const int lrow = l >> 3;        // staging: row within 8-row group
  // staging source column, pre-swizzled so that linear LDS dest ends up
  // holding logical col ( (l&7)*8 ^ (row&7)*8 ) at physical col (l&7)*8:
  const int scol = ((l & 7) ^ lrow) * 8;

  f32x4 acc[4][4] = {};

  // --- staging: 8 global_load_lds(16B) per wave per stage -----------------
  auto stage = [&](int buf, int s) {
    const int k = s >> 1;
    const int hOff = (s & 1) << 6;  // 0 or 64
#pragma unroll
    for (int i = 0; i < 4; ++i) {
      const int rg = wv * 32 + i * 8;        // 8-row group base
      const int rr = rg + lrow;
      const int ix = (int)ridx[rr * KK + k];
      const __hip_bfloat16* ga =
          (ix >= 0) ? (xb + (size_t)ix * CC + hOff + scol) : (zr + scol);
      gll16(ga, &As[buf][rg * BK]);
      const __hip_bfloat16* gb =
          wT + (size_t)k * (CC * CC) + (size_t)rr * CC + hOff + scol;
      gll16(gb, &Bs[buf][rg * BK]);
    }
  };

  // --- compute: 16 swizzled ds_read_b128 + 32 MFMA per wave per stage -----
  auto compute = [&](int buf) {
    const int sw = (lr & 7) * 8;  // row&7 == lr&7 for all frag rows below
#pragma unroll
    for (int kc = 0; kc < 2; ++kc) {
      const int ce = (kc * 32 + lk) ^ sw;  // swizzled column (elements)
      bf16x8 a[4], bb[4];
#pragma unroll
      for (int m = 0; m < 4; ++m)
        a[m] = *reinterpret_cast<const bf16x8*>(
            &As[buf][(wr * 64 + m * 16 + lr) * BK + ce]);
#pragma unroll
      for (int n = 0; n < 4; ++n)
        bb[n] = *reinterpret_cast<const bf16x8*>(
            &Bs[buf][(wc * 64 + n * 16 + lr) * BK + ce]);
#pragma unroll
      for (int m = 0; m < 4; ++m)
#pragma unroll
        for (int n = 0; n < 4; ++n)
          acc[m][n] =
              __builtin_amdgcn_mfma_f32_16x16x32_bf16(a[m], bb[n], acc[m][n],
                                                      0, 0, 0);
    }
  };

  // --- main loop: dbuf, 1 barrier per stage -------------------------------
  stage(0, 0);
  __syncthreads();  // drains vmcnt(0): buf0 ready
  int cur = 0;
#pragma unroll 2
  for (int s = 0; s < NSTAGE; ++s) {
    if (s + 1 < NSTAGE) stage(cur ^ 1, s + 1);
    compute(cur);
    __syncthreads();  // drains stage loads; protects buf reuse
    cur ^= 1;
  }

  // --- epilogue: C/D layout col=lane&15, row=(lane>>4)*4+q ---------------
  float bv[4];
#pragma unroll
  for (int n = 0; n < 4; ++n) bv[n] = bias[wc * 64 + n * 16 + lr];
  const int rbase = row0 + wr * 64 + (l >> 4) * 4;
#pragma unroll
  for (int m = 0; m < 4; ++m)
#pragma unroll
    for (int n = 0; n < 4; ++n)
#pragma unroll
      for (int q = 0; q < 4; ++q)
        out[(size_t)(rbase + m * 16 + q) * CC + wc * 64 + n * 16 + lr] =
            acc[m][n][q] + bv[n];
}

extern "C" void kernel_launch(void* const* d_in, const int* in_sizes, int n_in,
                              void* d_out, int out_size, void* d_ws,
                              size_t ws_size, hipStream_t stream) {
  const float* x = (const float*)d_in[0];
  const float* w = (const float*)d_in[1];
  const float* b = (const float*)d_in[2];
  const int* neigh = (const int*)d_in[3];
  __hip_bfloat16* ws = (__hip_bfloat16*)d_ws;
  float* out = (float*)d_out;

  hipLaunchKernelGGL(prep_kernel, dim3(512), dim3(256), 0, stream, x, w, ws);
  hipLaunchKernelGGL(upconv_kernel, dim3(N_CHILD / BM), dim3(256), 0, stream,
                     neigh, ws, b, out);
}

// Round 3
// 146.586 us; speedup vs baseline: 1.3847x; 1.0236x over previous
//
#include <hip/hip_runtime.h>
#include <hip/hip_bf16.h>

// Problem constants (from reference)
#define N_PARENT 16384
#define N_CHILD (8 * N_PARENT)   // 131072
#define CC 128                   // channels
#define KK 27                    // stencil taps

// GEMM tiling
#define BM 128                   // child rows per block
#define BK 64                    // c-slice per stage (half a channel row)
#define NSTAGE (KK * 2)          // 54 stages

// ws layout (bf16 element offsets)
#define XB_OFF 0
#define XB_ELEMS (N_PARENT * CC)             // 2,097,152
#define WT_OFF XB_ELEMS
#define WT_ELEMS (KK * CC * CC)              // 442,368
#define ZR_OFF (WT_OFF + WT_ELEMS)
#define ZR_ELEMS 128

typedef __attribute__((ext_vector_type(8))) __bf16 bf16x8;
typedef __attribute__((ext_vector_type(4))) float f32x4;

__device__ __forceinline__ void gll16(const void* g, void* l) {
  __builtin_amdgcn_global_load_lds(
      (const __attribute__((address_space(1))) unsigned int*)g,
      (__attribute__((address_space(3))) unsigned int*)l,
      16, 0, 0);
}

// Cast x to bf16, build w^T[k][d][c] in bf16, zero row. Runs every launch
// (ws is poisoned before timing; kernel_launch must be deterministic).
__global__ void prep_kernel(const float* __restrict__ x,
                            const float* __restrict__ w,
                            __hip_bfloat16* __restrict__ ws) {
  const int stride = gridDim.x * blockDim.x;
  const int tid = blockIdx.x * blockDim.x + threadIdx.x;
  for (int i = tid; i < XB_ELEMS; i += stride)
    ws[XB_OFF + i] = __float2bfloat16(x[i]);
  for (int j = tid; j < WT_ELEMS; j += stride) {
    const int k = j / (CC * CC);
    const int rem = j - k * CC * CC;
    const int d = rem >> 7;   // output channel
    const int c = rem & 127;  // input channel
    ws[WT_OFF + j] = __float2bfloat16(w[k * CC * CC + c * CC + d]);
  }
  if (tid < ZR_ELEMS) ws[ZR_OFF + tid] = __float2bfloat16(0.0f);
}

// LDS logical layout: tile[row][col] (row stride BK=64 bf16 = 128 B).
// Physical col swizzle: phys_col_elem = log_col_elem ^ ((row&7)*8).
// Staging keeps the LDS dest LINEAR (global_load_lds requirement) and applies
// the inverse permutation on the per-lane GLOBAL source column instead
// (rule #21: both-sides-or-neither).
//
// Main-loop sync (T4): counted vmcnt + raw barriers, no vmcnt(0) drain.
//   iter s: stage(s+1) [+8]; s_waitcnt vmcnt(8)  <- stage-s landed, s+1 in flight
//           s_barrier (B1, RAW: all waves' stage-s loads landed)
//           compute(s) under setprio(1)
//           s_barrier (B2, WAR: all waves done reading buf before next write)
__global__ __launch_bounds__(256, 2) void upconv_kernel(
    const int* __restrict__ neigh,
    const __hip_bfloat16* __restrict__ ws,
    const float* __restrict__ bias,
    float* __restrict__ out) {
  __shared__ __align__(16) __hip_bfloat16 As[2][BM * BK];   // 32 KB
  __shared__ __align__(16) __hip_bfloat16 Bs[2][CC * BK];   // 32 KB
  __shared__ short ridx[BM * KK];                           // 6.75 KB

  const __hip_bfloat16* xb = ws + XB_OFF;
  const __hip_bfloat16* wT = ws + WT_OFF;
  const __hip_bfloat16* zr = ws + ZR_OFF;

  const int tid = threadIdx.x;
  const int wv = tid >> 6;   // wave 0..3
  const int l = tid & 63;    // lane
  const int wr = wv >> 1;    // wave row (2x2 wave grid, 64x64 per wave)
  const int wc = wv & 1;     // wave col
  const int row0 = blockIdx.x * BM;

  // Preload neighbor indices (coalesced), pre-shifted to parent rows.
  for (int j = tid; j < BM * KK; j += 256) {
    const int nv = neigh[row0 * KK + j];
    ridx[j] = (short)((nv >= 0) ? (nv >> 3) : -1);
  }
  __syncthreads();  // full drain once; in-loop vmcnt counts only gll16s

  const int lr = l & 15;          // frag row/col within 16
  const int lk = (l >> 4) * 8;    // frag k-chunk offset (elements)
  const int lrow = l >> 3;        // staging: row within 8-row group
  // staging source column, pre-swizzled so that linear LDS dest ends up
  // holding logical col ( (l&7)*8 ^ (row&7)*8 ) at physical col (l&7)*8:
  const int scol = ((l & 7) ^ lrow) * 8;

  f32x4 acc[4][4] = {};

  // --- staging: 8 global_load_lds(16B) per wave per stage -----------------
  auto stage = [&](int buf, int s) {
    const int k = s >> 1;
    const int hOff = (s & 1) << 6;  // 0 or 64
#pragma unroll
    for (int i = 0; i < 4; ++i) {
      const int rg = wv * 32 + i * 8;        // 8-row group base
      const int rr = rg + lrow;
      const int ix = (int)ridx[rr * KK + k];
      const __hip_bfloat16* ga =
          (ix >= 0) ? (xb + (size_t)ix * CC + hOff + scol) : (zr + scol);
      gll16(ga, &As[buf][rg * BK]);
      const __hip_bfloat16* gb =
          wT + (size_t)k * (CC * CC) + (size_t)rr * CC + hOff + scol;
      gll16(gb, &Bs[buf][rg * BK]);
    }
  };

  // --- compute: 16 swizzled ds_read_b128 + 32 MFMA per wave per stage -----
  auto compute = [&](int buf) {
    const int sw = (lr & 7) * 8;  // row&7 == lr&7 for all frag rows below
#pragma unroll
    for (int kc = 0; kc < 2; ++kc) {
      const int ce = (kc * 32 + lk) ^ sw;  // swizzled column (elements)
      bf16x8 a[4], bb[4];
#pragma unroll
      for (int m = 0; m < 4; ++m)
        a[m] = *reinterpret_cast<const bf16x8*>(
            &As[buf][(wr * 64 + m * 16 + lr) * BK + ce]);
#pragma unroll
      for (int n = 0; n < 4; ++n)
        bb[n] = *reinterpret_cast<const bf16x8*>(
            &Bs[buf][(wc * 64 + n * 16 + lr) * BK + ce]);
#pragma unroll
      for (int m = 0; m < 4; ++m)
#pragma unroll
        for (int n = 0; n < 4; ++n)
          acc[m][n] =
              __builtin_amdgcn_mfma_f32_16x16x32_bf16(a[m], bb[n], acc[m][n],
                                                      0, 0, 0);
    }
  };

  // --- main loop: dbuf, counted vmcnt, 2 raw barriers per stage -----------
  stage(0, 0);  // 8 outstanding
  for (int s = 0; s < NSTAGE; ++s) {
    const int cur = s & 1;
    if (s + 1 < NSTAGE) {
      stage(cur ^ 1, s + 1);  // +8 -> 16 outstanding
      asm volatile("s_waitcnt vmcnt(8)" ::: "memory");  // stage-s landed
    } else {
      asm volatile("s_waitcnt vmcnt(0)" ::: "memory");  // last stage landed
    }
    __builtin_amdgcn_s_barrier();  // B1: RAW — all waves' stage-s landed
    __builtin_amdgcn_s_setprio(1);
    compute(cur);
    __builtin_amdgcn_s_setprio(0);
    __builtin_amdgcn_s_barrier();  // B2: WAR — all reads of buf done
  }

  // --- epilogue: C/D layout col=lane&15, row=(lane>>4)*4+q ---------------
  float bv[4];
#pragma unroll
  for (int n = 0; n < 4; ++n) bv[n] = bias[wc * 64 + n * 16 + lr];
  const int rbase = row0 + wr * 64 + (l >> 4) * 4;
#pragma unroll
  for (int m = 0; m < 4; ++m)
#pragma unroll
    for (int n = 0; n < 4; ++n)
#pragma unroll
      for (int q = 0; q < 4; ++q)
        out[(size_t)(rbase + m * 16 + q) * CC + wc * 64 + n * 16 + lr] =
            acc[m][n][q] + bv[n];
}

extern "C" void kernel_launch(void* const* d_in, const int* in_sizes, int n_in,
                              void* d_out, int out_size, void* d_ws,
                              size_t ws_size, hipStream_t stream) {
  const float* x = (const float*)d_in[0];
  const float* w = (const float*)d_in[1];
  const float* b = (const float*)d_in[2];
  const int* neigh = (const int*)d_in[3];
  __hip_bfloat16* ws = (__hip_bfloat16*)d_ws;
  float* out = (float*)d_out;

  hipLaunchKernelGGL(prep_kernel, dim3(512), dim3(256), 0, stream, x, w, ws);
  hipLaunchKernelGGL(upconv_kernel, dim3(N_CHILD / BM), dim3(256), 0, stream,
                     neigh, ws, b, out);
}